// Round 13
// baseline (478.814 us; speedup 1.0000x reference)
//
#include <hip/hip_runtime.h>
#include <hip/hip_bf16.h>

#define BS_   2048
#define HID_  512
#define PH_   32

typedef _Float16 half8 __attribute__((ext_vector_type(8)));
typedef float floatx4 __attribute__((ext_vector_type(4)));

__device__ __forceinline__ float sigf(float x) { return 1.f / (1.f + __expf(-x)); }
__device__ __forceinline__ float tanhfast(float x) {
    float e = __expf(2.f * x);          // e=inf -> 1, e->0 -> -1 : safe at extremes
    return 1.f - 2.f / (e + 1.f);
}

// ---------------------------------------------------------------------------
// Prep: fp16 weights (W_ih, W_ih+W_hh), combined bias, z16, zero flag lines.
// Flags: flag[ib][j] at cnt[(ib*32 + j)*16] -- 16 tiles x 32 producers, one
// 64B line each = 8192 ints.
// ---------------------------------------------------------------------------
__global__ __launch_bounds__(256) void prep_kernel(
    const float* __restrict__ Wih, const float* __restrict__ Whh,
    const float* __restrict__ bih, const float* __restrict__ bhh,
    const float* __restrict__ z,
    _Float16* __restrict__ wih16, _Float16* __restrict__ wsum16,
    _Float16* __restrict__ z16, float* __restrict__ bsum,
    int* __restrict__ cnt)
{
    int i = blockIdx.x * 256 + threadIdx.x;          // [0, 1048576)
    if (i < BS_ * HID_) z16[i] = (_Float16)z[i];
    if (i < 4 * HID_ * HID_) {
        float a = Wih[i];
        wih16[i]  = (_Float16)a;
        wsum16[i] = (_Float16)(a + Whh[i]);
    }
    if (i < 4 * HID_) bsum[i] = bih[i] + bhh[i];
    if (i < 8192) cnt[i] = 0;
}

// ---------------------------------------------------------------------------
// Stage a 16-hid weight slice: 64 gate rows x 512 K fp16 = 64 KB LDS,
// XOR-swizzled on 16B blocks (R6-proven).
// ---------------------------------------------------------------------------
__device__ __forceinline__ void stage_weights(_Float16* Wl, const _Float16* Wg,
                                              int j, int tid)
{
#pragma unroll
    for (int rep = 0; rep < 8; ++rep) {
        int idx = rep * 512 + tid;      // [0, 4096): row n in [0,64), kb in [0,64)
        int n  = idx >> 6;
        int kb = idx & 63;
        int g  = n >> 4, u = n & 15;    // gate, hid-within-slice
        const half8* src = (const half8*)(Wg + ((size_t)(g * HID_ + j * 16 + u)) * HID_ + kb * 8);
        int phys = (kb & 56) | ((kb & 7) ^ (n & 7));
        *(half8*)((char*)Wl + n * 1024 + phys * 16) = *src;
    }
}

// ---------------------------------------------------------------------------
// One tile-step: gates GEMM [128 x 64 x 512] for batch tile ib (this wave:
// M=16 strip), LSTM pointwise, agent-scope WT h-stores. R6-proven inner loop
// (depth-4 A ring from global, double-buffered B from LDS, bias pre-folded).
// ---------------------------------------------------------------------------
__device__ __forceinline__ void compute_tile(
    const _Float16* __restrict__ xx, int ib, const char* Bl, int tE,
    int ln, int qw, int wv, const float* bias, float* c,
    _Float16* __restrict__ hs_t, int hid)
{
    floatx4 acc[4];
#pragma unroll
    for (int g = 0; g < 4; ++g)
        acc[g] = (floatx4){bias[g], bias[g], bias[g], bias[g]};

    // A fragment: A[m = ln][k = qw*8 + jj]
    const _Float16* A0 = xx + (size_t)(ib * 128 + wv * 16 + ln) * HID_ + qw * 8;

    half8 ar[4], bA[4], bB[4];
#pragma unroll
    for (int p = 0; p < 4; ++p) ar[p] = *(const half8*)(A0 + p * 32);
#pragma unroll
    for (int g = 0; g < 4; ++g)
        bA[g] = *(const half8*)(Bl + (g * 16 + ln) * 1024 + tE);

#pragma unroll
    for (int kk = 0; kk < 16; ++kk) {
        half8 ca = ar[kk & 3];
        if (kk < 12) ar[kk & 3] = *(const half8*)(A0 + (kk + 4) * 32);
        half8* cb = (kk & 1) ? bB : bA;
        half8* nb = (kk & 1) ? bA : bB;
        if (kk < 15) {
            int k1 = kk + 1;
#pragma unroll
            for (int g = 0; g < 4; ++g) {
                int off = (g * 16 + ln) * 1024 + (k1 >> 1) * 128 + (tE ^ ((k1 & 1) << 6));
                nb[g] = *(const half8*)(Bl + off);
            }
        }
#pragma unroll
        for (int g = 0; g < 4; ++g)
            acc[g] = __builtin_amdgcn_mfma_f32_16x16x32_f16(ca, cb[g], acc[g], 0, 0, 0);
    }

    // epilogue: C/D layout col=ln, row=qw*4+r; all 4 gates in-thread.
    _Float16* hb = hs_t + (size_t)(ib * 128 + wv * 16 + qw * 4) * HID_ + hid;
#pragma unroll
    for (int r = 0; r < 4; ++r) {
        float gi = acc[0][r];
        float gf = acc[1][r];
        float gg = acc[2][r];
        float go = acc[3][r];
        float cn = sigf(gf) * c[r] + sigf(gi) * tanhfast(gg);
        float hn = sigf(go) * tanhfast(cn);
        c[r] = cn;
        _Float16 hf = (_Float16)hn;
        short hv;
        __builtin_memcpy(&hv, &hf, 2);
        __hip_atomic_store((short*)(hb + (size_t)r * HID_), hv,
                           __ATOMIC_RELAXED, __HIP_MEMORY_SCOPE_AGENT);
    }
}

// ---------------------------------------------------------------------------
// Persistent LSTM, TWO PHASE-OFFSET TILES per block: the R12 chain latency
// (~6us/step: drain -> CP signal visibility -> poll -> A-fetch) hides behind
// the OTHER tile's compute.
//
// Grid = 256 x 512 = 32 j-slices (16 hid, 64 KB LDS weights, R6 geometry)
// x 8 p. Block (j,p) owns batch tiles ibA=2p, ibB=2p+1 (128 rows each; same
// weights). Per step: waitA -> computeA -> drain+signalA -> waitB ->
// computeB -> drain+signalB. Chains are linear (signal X(t-1) precedes any
// wait on the other tile) -- no deadlock; exposed wait ~= max(0, chain -
// compute_other).
//
// Sync protocol (R6/R9/R12-proven, block-level only): producer h stores are
// agent-scope WT (coherence point); __syncthreads drains vmcnt; tid0
// fetch_add(+1) on its own uncontended 64B flag line. Consumer: wave 0,
// lanes 0..31 each poll one producer line with a relaxed CP-RMW (plain loads
// go stale -- R2), __all-vote >= t, __syncthreads releases. Per-wave/chunked
// polling regressed 4-27x (R7/R8/R11) -- never re-attempt. XCD-locality
// gating failed 3x (R4/R5/R10) -- abandoned.
// ---------------------------------------------------------------------------
__global__ __launch_bounds__(512) void lstm_persist(
    const _Float16* __restrict__ wih16, const _Float16* __restrict__ wsum16,
    const float* __restrict__ bsum, const _Float16* __restrict__ z16,
    _Float16* __restrict__ hs, int* __restrict__ cnt)
{
    __shared__ _Float16 Wl[64 * 512];   // 64 KB

    const int tid  = threadIdx.x;
    const int j    = blockIdx.x & 31;
    const int p    = blockIdx.x >> 5;
    const int ibA  = 2 * p, ibB = 2 * p + 1;
    const int lane = tid & 63;
    const int wv   = tid >> 6;          // wave 0..7 -> 16-row M strip
    const int qw   = lane >> 4;         // quad 0..3
    const int ln   = lane & 15;
    const int hid  = j * 16 + ln;

    stage_weights(Wl, wih16, j, tid);

    float bias[4];
#pragma unroll
    for (int g = 0; g < 4; ++g) bias[g] = bsum[g * HID_ + hid];

    float c[2][4];
#pragma unroll
    for (int tl = 0; tl < 2; ++tl)
#pragma unroll
        for (int r = 0; r < 4; ++r) c[tl][r] = 0.f;

    const char* Bl = (const char*)Wl;
    const int tE = (qw ^ (ln & 7)) * 16;    // swizzled byte offset, kk-even

    __syncthreads();

    for (int t = 0; t < PH_; ++t) {
        const _Float16* xx = (t == 0) ? z16 : hs + (size_t)(t - 1) * BS_ * HID_;
        _Float16* hs_t = hs + (size_t)t * BS_ * HID_;

        // ---------------- tile A ----------------
        if (t >= 1) {
            if (wv == 0) {
                for (;;) {
                    int v = t;
                    if (lane < 32)
                        v = __hip_atomic_fetch_add(&cnt[(ibA * 32 + lane) * 16], 0,
                                                   __ATOMIC_RELAXED,
                                                   __HIP_MEMORY_SCOPE_AGENT);
                    if (__all(v >= t)) break;
                    __builtin_amdgcn_s_sleep(1);
                }
            }
            __syncthreads();
        }
        compute_tile(xx, ibA, Bl, tE, ln, qw, wv, bias, c[0], hs_t, hid);
        __syncthreads();                    // drain WT stores (vmcnt(0) -> CP ack)
        if (tid == 0 && t < PH_ - 1)
            __hip_atomic_fetch_add(&cnt[(ibA * 32 + j) * 16], 1,
                                   __ATOMIC_RELAXED, __HIP_MEMORY_SCOPE_AGENT);

        // ---------------- tile B ----------------
        if (t >= 1) {
            if (wv == 0) {
                for (;;) {
                    int v = t;
                    if (lane < 32)
                        v = __hip_atomic_fetch_add(&cnt[(ibB * 32 + lane) * 16], 0,
                                                   __ATOMIC_RELAXED,
                                                   __HIP_MEMORY_SCOPE_AGENT);
                    if (__all(v >= t)) break;
                    __builtin_amdgcn_s_sleep(1);
                }
            }
            __syncthreads();
        }
        compute_tile(xx, ibB, Bl, tE, ln, qw, wv, bias, c[1], hs_t, hid);
        __syncthreads();                    // drain WT stores
        if (tid == 0 && t < PH_ - 1)
            __hip_atomic_fetch_add(&cnt[(ibB * 32 + j) * 16], 1,
                                   __ATOMIC_RELAXED, __HIP_MEMORY_SCOPE_AGENT);

        if (t == 0) {
            stage_weights(Wl, wsum16, j, tid);   // switch to W_ih+W_hh (once)
            __syncthreads();
        }
    }
}

// ---------------------------------------------------------------------------
// y[b,t,:] = hs[t][b,:] @ W_d^T + b_d. One wave per (b,t) row.
// ---------------------------------------------------------------------------
__global__ __launch_bounds__(256) void dense_kernel(
    const _Float16* __restrict__ hs, const float* __restrict__ Wd,
    const float* __restrict__ bd, float* __restrict__ y)
{
    int gw   = (blockIdx.x * 256 + threadIdx.x) >> 6;   // wave id [0, 65536)
    int lane = threadIdx.x & 63;
    int tt = gw & 31, b = gw >> 5;
    half8 h = *(const half8*)(hs + ((size_t)tt * BS_ + b) * HID_ + lane * 8);
    float s0 = 0.f, s1 = 0.f;
#pragma unroll
    for (int k = 0; k < 8; ++k) {
        float hv = (float)h[k];
        s0 += hv * Wd[lane * 8 + k];
        s1 += hv * Wd[HID_ + lane * 8 + k];
    }
#pragma unroll
    for (int m = 32; m >= 1; m >>= 1) {
        s0 += __shfl_xor(s0, m);
        s1 += __shfl_xor(s1, m);
    }
    if (lane == 0) {
        float* o = y + ((size_t)b * PH_ + tt) * 2;
        o[0] = s0 + bd[0];
        o[1] = s1 + bd[1];
    }
}

// ---------------------------------------------------------------------------
extern "C" void kernel_launch(void* const* d_in, const int* in_sizes, int n_in,
                              void* d_out, int out_size, void* d_ws, size_t ws_size,
                              hipStream_t stream)
{
    (void)in_sizes; (void)n_in; (void)out_size; (void)ws_size;
    // setup_inputs order: hist(0, unused), z(1), W_ih(2), W_hh(3), b_ih(4),
    //                     b_hh(5), W_d(6), b_d(7)
    const float* z   = (const float*)d_in[1];
    const float* Wih = (const float*)d_in[2];
    const float* Whh = (const float*)d_in[3];
    const float* bih = (const float*)d_in[4];
    const float* bhh = (const float*)d_in[5];
    const float* Wd  = (const float*)d_in[6];
    const float* bd  = (const float*)d_in[7];
    float* y = (float*)d_out;

    char* ws = (char*)d_ws;
    _Float16* hs     = (_Float16*)ws;                          // 64 MB
    _Float16* z16    = (_Float16*)(ws + (size_t)67108864);     // 2 MB
    _Float16* wih16  = (_Float16*)(ws + (size_t)69206016);     // 2 MB
    _Float16* wsum16 = (_Float16*)(ws + (size_t)71303168);     // 2 MB
    float*    bsum   = (float*)   (ws + (size_t)73400320);     // 8 KB
    int*      cnt    = (int*)     (ws + (size_t)73408512);     // 8192 ints (32 KB)

    prep_kernel<<<4096, 256, 0, stream>>>(Wih, Whh, bih, bhh, z,
                                          wih16, wsum16, z16, bsum, cnt);

    {
        const void* k = (const void*)lstm_persist;
        void* args[] = {(void*)&wih16, (void*)&wsum16, (void*)&bsum,
                        (void*)&z16, (void*)&hs, (void*)&cnt};
        hipLaunchCooperativeKernel(k, dim3(256), dim3(512), args, 0, stream);
    }

    dense_kernel<<<16384, 256, 0, stream>>>(hs, Wd, bd, y);
}

// Round 14
// 470.313 us; speedup vs baseline: 1.0181x; 1.0181x over previous
//
#include <hip/hip_runtime.h>
#include <hip/hip_bf16.h>

#define BS_   2048
#define HID_  512
#define PH_   32

typedef _Float16 half8 __attribute__((ext_vector_type(8)));
typedef float floatx4 __attribute__((ext_vector_type(4)));

__device__ __forceinline__ float sigf(float x) { return 1.f / (1.f + __expf(-x)); }
__device__ __forceinline__ float tanhfast(float x) {
    float e = __expf(2.f * x);          // e=inf -> 1, e->0 -> -1 : safe at extremes
    return 1.f - 2.f / (e + 1.f);
}

// ---------------------------------------------------------------------------
// Prep: fp16 weights (W_ih, W_ih+W_hh), combined bias, z16, zero flag lines.
// Flags: flag[ib][j] at cnt[(ib*32 + j)*16] -- 16 tiles x 32 producers, one
// 64B line each = 8192 ints.
// ---------------------------------------------------------------------------
__global__ __launch_bounds__(256) void prep_kernel(
    const float* __restrict__ Wih, const float* __restrict__ Whh,
    const float* __restrict__ bih, const float* __restrict__ bhh,
    const float* __restrict__ z,
    _Float16* __restrict__ wih16, _Float16* __restrict__ wsum16,
    _Float16* __restrict__ z16, float* __restrict__ bsum,
    int* __restrict__ cnt)
{
    int i = blockIdx.x * 256 + threadIdx.x;          // [0, 1048576)
    if (i < BS_ * HID_) z16[i] = (_Float16)z[i];
    if (i < 4 * HID_ * HID_) {
        float a = Wih[i];
        wih16[i]  = (_Float16)a;
        wsum16[i] = (_Float16)(a + Whh[i]);
    }
    if (i < 4 * HID_) bsum[i] = bih[i] + bhh[i];
    if (i < 8192) cnt[i] = 0;
}

// ---------------------------------------------------------------------------
// Stage a 16-hid weight slice: 64 gate rows x 512 K fp16 = 64 KB LDS,
// XOR-swizzled on 16B blocks (R6-proven).
// ---------------------------------------------------------------------------
__device__ __forceinline__ void stage_weights(_Float16* Wl, const _Float16* Wg,
                                              int j, int tid)
{
#pragma unroll
    for (int rep = 0; rep < 8; ++rep) {
        int idx = rep * 512 + tid;      // [0, 4096): row n in [0,64), kb in [0,64)
        int n  = idx >> 6;
        int kb = idx & 63;
        int g  = n >> 4, u = n & 15;    // gate, hid-within-slice
        const half8* src = (const half8*)(Wg + ((size_t)(g * HID_ + j * 16 + u)) * HID_ + kb * 8);
        int phys = (kb & 56) | ((kb & 7) ^ (n & 7));
        *(half8*)((char*)Wl + n * 1024 + phys * 16) = *src;
    }
}

// ---------------------------------------------------------------------------
// One tile-step: gates GEMM [128 x 64 x 512] for batch tile ib (this wave:
// M=16 strip), LSTM pointwise, agent-scope WT h-stores. R6-proven inner loop
// (depth-4 A ring from global, double-buffered B from LDS, bias pre-folded).
// ---------------------------------------------------------------------------
__device__ __forceinline__ void compute_tile(
    const _Float16* __restrict__ xx, int ib, const char* Bl, int tE,
    int ln, int qw, int wv, const float* bias, float* c,
    _Float16* __restrict__ hs_t, int hid)
{
    floatx4 acc[4];
#pragma unroll
    for (int g = 0; g < 4; ++g)
        acc[g] = (floatx4){bias[g], bias[g], bias[g], bias[g]};

    // A fragment: A[m = ln][k = qw*8 + jj]
    const _Float16* A0 = xx + (size_t)(ib * 128 + wv * 16 + ln) * HID_ + qw * 8;

    half8 ar[4], bA[4], bB[4];
#pragma unroll
    for (int p = 0; p < 4; ++p) ar[p] = *(const half8*)(A0 + p * 32);
#pragma unroll
    for (int g = 0; g < 4; ++g)
        bA[g] = *(const half8*)(Bl + (g * 16 + ln) * 1024 + tE);

#pragma unroll
    for (int kk = 0; kk < 16; ++kk) {
        half8 ca = ar[kk & 3];
        if (kk < 12) ar[kk & 3] = *(const half8*)(A0 + (kk + 4) * 32);
        half8* cb = (kk & 1) ? bB : bA;
        half8* nb = (kk & 1) ? bA : bB;
        if (kk < 15) {
            int k1 = kk + 1;
#pragma unroll
            for (int g = 0; g < 4; ++g) {
                int off = (g * 16 + ln) * 1024 + (k1 >> 1) * 128 + (tE ^ ((k1 & 1) << 6));
                nb[g] = *(const half8*)(Bl + off);
            }
        }
#pragma unroll
        for (int g = 0; g < 4; ++g)
            acc[g] = __builtin_amdgcn_mfma_f32_16x16x32_f16(ca, cb[g], acc[g], 0, 0, 0);
    }

    // epilogue: C/D layout col=ln, row=qw*4+r; all 4 gates in-thread.
    _Float16* hb = hs_t + (size_t)(ib * 128 + wv * 16 + qw * 4) * HID_ + hid;
#pragma unroll
    for (int r = 0; r < 4; ++r) {
        float gi = acc[0][r];
        float gf = acc[1][r];
        float gg = acc[2][r];
        float go = acc[3][r];
        float cn = sigf(gf) * c[r] + sigf(gi) * tanhfast(gg);
        float hn = sigf(go) * tanhfast(cn);
        c[r] = cn;
        _Float16 hf = (_Float16)hn;
        short hv;
        __builtin_memcpy(&hv, &hf, 2);
        __hip_atomic_store((short*)(hb + (size_t)r * HID_), hv,
                           __ATOMIC_RELAXED, __HIP_MEMORY_SCOPE_AGENT);
    }
}

// ---------------------------------------------------------------------------
// Persistent LSTM, two phase-offset tiles per block (R13) + XCD-CO-LOCATED
// groups (the R13 regression root-cause, fixed):
//   p = blockIdx & 7, j = blockIdx >> 3  -->  group p's 32 j-blocks all have
//   blockIdx == p (mod 8) --> one XCD under round-robin dispatch. Its two
//   tiles' A-planes are fetched ONCE per step into that XCD's L2 and shared
//   by the 32 blocks (R9/R6's low FETCH was this same arithmetic accident:
//   ib = blockIdx & 15 => XCD = ib % 8).
//
// Per step: waitA -> computeA -> drain+signalA -> waitB -> computeB ->
// drain+signalB. The sync-chain latency of each tile hides behind the other
// tile's compute (R13-proven: absorbed even 8x A-traffic at only +17%).
//
// Sync protocol (R6/R9/R12-proven, block-level only): producer h stores are
// agent-scope WT (coherence point); __syncthreads drains vmcnt; tid0
// fetch_add(+1) on its own uncontended 64B flag line. Consumer: wave 0,
// lanes 0..31 each poll one producer line with a relaxed CP-RMW (plain loads
// go stale -- R2), __all-vote >= t, __syncthreads releases. Per-wave/chunked
// polling regressed 4-27x (R7/R8/R11) -- never re-attempt.
// ---------------------------------------------------------------------------
__global__ __launch_bounds__(512) void lstm_persist(
    const _Float16* __restrict__ wih16, const _Float16* __restrict__ wsum16,
    const float* __restrict__ bsum, const _Float16* __restrict__ z16,
    _Float16* __restrict__ hs, int* __restrict__ cnt)
{
    __shared__ _Float16 Wl[64 * 512];   // 64 KB

    const int tid  = threadIdx.x;
    const int p    = blockIdx.x & 7;    // XCD co-location: group == XCD
    const int j    = blockIdx.x >> 3;
    const int ibA  = 2 * p, ibB = 2 * p + 1;
    const int lane = tid & 63;
    const int wv   = tid >> 6;          // wave 0..7 -> 16-row M strip
    const int qw   = lane >> 4;         // quad 0..3
    const int ln   = lane & 15;
    const int hid  = j * 16 + ln;

    stage_weights(Wl, wih16, j, tid);

    float bias[4];
#pragma unroll
    for (int g = 0; g < 4; ++g) bias[g] = bsum[g * HID_ + hid];

    float c[2][4];
#pragma unroll
    for (int tl = 0; tl < 2; ++tl)
#pragma unroll
        for (int r = 0; r < 4; ++r) c[tl][r] = 0.f;

    const char* Bl = (const char*)Wl;
    const int tE = (qw ^ (ln & 7)) * 16;    // swizzled byte offset, kk-even

    __syncthreads();

    for (int t = 0; t < PH_; ++t) {
        const _Float16* xx = (t == 0) ? z16 : hs + (size_t)(t - 1) * BS_ * HID_;
        _Float16* hs_t = hs + (size_t)t * BS_ * HID_;

        // ---------------- tile A ----------------
        if (t >= 1) {
            if (wv == 0) {
                for (;;) {
                    int v = t;
                    if (lane < 32)
                        v = __hip_atomic_fetch_add(&cnt[(ibA * 32 + lane) * 16], 0,
                                                   __ATOMIC_RELAXED,
                                                   __HIP_MEMORY_SCOPE_AGENT);
                    if (__all(v >= t)) break;
                    __builtin_amdgcn_s_sleep(1);
                }
            }
            __syncthreads();
        }
        compute_tile(xx, ibA, Bl, tE, ln, qw, wv, bias, c[0], hs_t, hid);
        __syncthreads();                    // drain WT stores (vmcnt(0) -> CP ack)
        if (tid == 0 && t < PH_ - 1)
            __hip_atomic_fetch_add(&cnt[(ibA * 32 + j) * 16], 1,
                                   __ATOMIC_RELAXED, __HIP_MEMORY_SCOPE_AGENT);

        // ---------------- tile B ----------------
        if (t >= 1) {
            if (wv == 0) {
                for (;;) {
                    int v = t;
                    if (lane < 32)
                        v = __hip_atomic_fetch_add(&cnt[(ibB * 32 + lane) * 16], 0,
                                                   __ATOMIC_RELAXED,
                                                   __HIP_MEMORY_SCOPE_AGENT);
                    if (__all(v >= t)) break;
                    __builtin_amdgcn_s_sleep(1);
                }
            }
            __syncthreads();
        }
        compute_tile(xx, ibB, Bl, tE, ln, qw, wv, bias, c[1], hs_t, hid);
        __syncthreads();                    // drain WT stores
        if (tid == 0 && t < PH_ - 1)
            __hip_atomic_fetch_add(&cnt[(ibB * 32 + j) * 16], 1,
                                   __ATOMIC_RELAXED, __HIP_MEMORY_SCOPE_AGENT);

        if (t == 0) {
            stage_weights(Wl, wsum16, j, tid);   // switch to W_ih+W_hh (once)
            __syncthreads();
        }
    }
}

// ---------------------------------------------------------------------------
// y[b,t,:] = hs[t][b,:] @ W_d^T + b_d. One wave per (b,t) row.
// ---------------------------------------------------------------------------
__global__ __launch_bounds__(256) void dense_kernel(
    const _Float16* __restrict__ hs, const float* __restrict__ Wd,
    const float* __restrict__ bd, float* __restrict__ y)
{
    int gw   = (blockIdx.x * 256 + threadIdx.x) >> 6;   // wave id [0, 65536)
    int lane = threadIdx.x & 63;
    int tt = gw & 31, b = gw >> 5;
    half8 h = *(const half8*)(hs + ((size_t)tt * BS_ + b) * HID_ + lane * 8);
    float s0 = 0.f, s1 = 0.f;
#pragma unroll
    for (int k = 0; k < 8; ++k) {
        float hv = (float)h[k];
        s0 += hv * Wd[lane * 8 + k];
        s1 += hv * Wd[HID_ + lane * 8 + k];
    }
#pragma unroll
    for (int m = 32; m >= 1; m >>= 1) {
        s0 += __shfl_xor(s0, m);
        s1 += __shfl_xor(s1, m);
    }
    if (lane == 0) {
        float* o = y + ((size_t)b * PH_ + tt) * 2;
        o[0] = s0 + bd[0];
        o[1] = s1 + bd[1];
    }
}

// ---------------------------------------------------------------------------
extern "C" void kernel_launch(void* const* d_in, const int* in_sizes, int n_in,
                              void* d_out, int out_size, void* d_ws, size_t ws_size,
                              hipStream_t stream)
{
    (void)in_sizes; (void)n_in; (void)out_size; (void)ws_size;
    // setup_inputs order: hist(0, unused), z(1), W_ih(2), W_hh(3), b_ih(4),
    //                     b_hh(5), W_d(6), b_d(7)
    const float* z   = (const float*)d_in[1];
    const float* Wih = (const float*)d_in[2];
    const float* Whh = (const float*)d_in[3];
    const float* bih = (const float*)d_in[4];
    const float* bhh = (const float*)d_in[5];
    const float* Wd  = (const float*)d_in[6];
    const float* bd  = (const float*)d_in[7];
    float* y = (float*)d_out;

    char* ws = (char*)d_ws;
    _Float16* hs     = (_Float16*)ws;                          // 64 MB
    _Float16* z16    = (_Float16*)(ws + (size_t)67108864);     // 2 MB
    _Float16* wih16  = (_Float16*)(ws + (size_t)69206016);     // 2 MB
    _Float16* wsum16 = (_Float16*)(ws + (size_t)71303168);     // 2 MB
    float*    bsum   = (float*)   (ws + (size_t)73400320);     // 8 KB
    int*      cnt    = (int*)     (ws + (size_t)73408512);     // 8192 ints (32 KB)

    prep_kernel<<<4096, 256, 0, stream>>>(Wih, Whh, bih, bhh, z,
                                          wih16, wsum16, z16, bsum, cnt);

    {
        const void* k = (const void*)lstm_persist;
        void* args[] = {(void*)&wih16, (void*)&wsum16, (void*)&bsum,
                        (void*)&z16, (void*)&hs, (void*)&cnt};
        hipLaunchCooperativeKernel(k, dim3(256), dim3(512), args, 0, stream);
    }

    dense_kernel<<<16384, 256, 0, stream>>>(hs, Wd, bd, y);
}